// Round 3
// baseline (28726.721 us; speedup 1.0000x reference)
//
#include <hip/hip_runtime.h>
#include <math.h>

#define N_ROWS   16384
#define K_EMB    8192
#define C_DIM    256
#define QUANT_N  4194304      // 16*256*32*32
#define QUANT_OFF 1
#define PERP_OFF  4194305
#define ENC_OFF   4194306

#define NSPLIT   8            // K split factor (grid = 128 rowblocks * NSPLIT)

// ws layout in 4-byte units
#define WS_BK    0                         // 8192 f32
#define WS_AMIN  8192                      // 16384 u64 (packed d|k) = 32768 f32 slots
#define WS_IDX   (WS_AMIN + 2 * N_ROWS)    // 16384 i32
#define WS_CNT   (WS_IDX + N_ROWS)         // 8192 i32
#define WS_ACC   (WS_CNT + K_EMB)          // 1 double (8B aligned: offset is even)

// ---------------- b_k = sum(emb[k,:]^2) ----------------
__global__ void vq_bk_kernel(const float* __restrict__ emb, float* __restrict__ bk) {
    int row  = blockIdx.x * 4 + (threadIdx.x >> 6);
    int lane = threadIdx.x & 63;
    float4 v = reinterpret_cast<const float4*>(emb)[(size_t)row * 64 + lane];
    float s = v.x * v.x + v.y * v.y + v.z * v.z + v.w * v.w;
#pragma unroll
    for (int o = 32; o > 0; o >>= 1) s += __shfl_down(s, o, 64);
    if (lane == 0) bk[row] = s;
}

// ---------------- main distance/argmin GEMM ----------------
// grid 1024: blockIdx>>3 = row block (128 rows), blockIdx&7 = K split (1024 each)
// split in LOW bits -> split s lands on XCD s -> e-slice (1MB) L2-resident per XCD
// block tile: 128 rows x 256 ks, microtile 8 rows x 16 ks, c staged in 16-chunks
__launch_bounds__(256, 4)
__global__ void vq_argmin_kernel(const float* __restrict__ xin,
                                 const float* __restrict__ emb,
                                 const float* __restrict__ bk,
                                 unsigned long long* __restrict__ amin) {
    __shared__ float x_lds[128][20];
    __shared__ float e_lds[256][20];
    __shared__ float a_lds[128];

    const int tid = threadIdx.x;
    const int tr  = tid & 15;    // row-group 0..15
    const int tk  = tid >> 4;    // k-group 0..15
    const int rb     = blockIdx.x >> 3;
    const int split  = blockIdx.x & (NSPLIT - 1);
    const int row0   = rb * 128;
    const int b_img  = row0 >> 10;         // batch index (1024 rows per image)
    const int n_off  = row0 & 1023;
    // flat[(row, c)] = inputs[b][c][h][w] = xin[b*256*1024 + c*1024 + (row&1023)]
    const float* xbase = xin + (size_t)b_img * (C_DIM * 1024) + n_off;

    float minv[8];
    int   mini[8];
    float a_reg[8];
#pragma unroll
    for (int rr = 0; rr < 8; ++rr) { minv[rr] = 3.402823466e38f; mini[rr] = 0; a_reg[rr] = 0.f; }
    if (tid < 128) a_lds[tid] = 0.f;

    const int k_begin = split * (K_EMB / NSPLIT);
    float m[8][16];

    for (int kt = 0; kt < (K_EMB / NSPLIT) / 256; ++kt) {   // 4 tiles of 256 k
        const int k0 = k_begin + kt * 256;
#pragma unroll
        for (int rr = 0; rr < 8; ++rr)
#pragma unroll
            for (int kk = 0; kk < 16; ++kk) m[rr][kk] = 0.f;

        for (int cc = 0; cc < 16; ++cc) {                   // 16 chunks of 16 c
            __syncthreads();
            // stage x tile: 128 rows x 16 c (coalesced: 64 consecutive r per lane-group)
            {
                int r  = tid & 127;
                int c0 = tid >> 7;
#pragma unroll
                for (int p = 0; p < 8; ++p)
                    x_lds[r][c0 + p * 2] = xbase[(size_t)(cc * 16 + c0 + p * 2) * 1024 + r];
            }
            // stage e tile: 256 k x 16 c via float4 (4 float4 per k-row)
            {
#pragma unroll
                for (int p = 0; p < 4; ++p) {
                    int idx = tid + p * 256;
                    int k   = idx >> 2;
                    int c4  = idx & 3;
                    float4 v = reinterpret_cast<const float4*>(emb)[(size_t)(k0 + k) * 64 + cc * 4 + c4];
                    *reinterpret_cast<float4*>(&e_lds[k][c4 * 4]) = v;
                }
            }
            __syncthreads();
            if (kt == 0 && tid < 128) {
                // row sums of x^2, strict ascending-c order (bitwise == rounds 1-2)
                float s = a_lds[tid];
#pragma unroll
                for (int c = 0; c < 16; ++c) { float xv = x_lds[tid][c]; s += xv * xv; }
                a_lds[tid] = s;
            }
            // compute: 8x16 micro-tile, float4 over c, ev staged in two halves of 8
#pragma unroll
            for (int c4 = 0; c4 < 4; ++c4) {
                float4 xv[8];
#pragma unroll
                for (int rr = 0; rr < 8; ++rr)
                    xv[rr] = *reinterpret_cast<const float4*>(&x_lds[tr + rr * 16][c4 * 4]);
                {
                    float4 ev[8];
#pragma unroll
                    for (int kk = 0; kk < 8; ++kk)
                        ev[kk] = *reinterpret_cast<const float4*>(&e_lds[tk + kk * 16][c4 * 4]);
#pragma unroll
                    for (int rr = 0; rr < 8; ++rr)
#pragma unroll
                        for (int kk = 0; kk < 8; ++kk) {
                            m[rr][kk] += xv[rr].x * ev[kk].x;
                            m[rr][kk] += xv[rr].y * ev[kk].y;
                            m[rr][kk] += xv[rr].z * ev[kk].z;
                            m[rr][kk] += xv[rr].w * ev[kk].w;
                        }
                }
                {
                    float4 ev[8];
#pragma unroll
                    for (int kk = 0; kk < 8; ++kk)
                        ev[kk] = *reinterpret_cast<const float4*>(&e_lds[128 + tk + kk * 16][c4 * 4]);
#pragma unroll
                    for (int rr = 0; rr < 8; ++rr)
#pragma unroll
                        for (int kk = 0; kk < 8; ++kk) {
                            m[rr][kk + 8] += xv[rr].x * ev[kk].x;
                            m[rr][kk + 8] += xv[rr].y * ev[kk].y;
                            m[rr][kk + 8] += xv[rr].z * ev[kk].z;
                            m[rr][kk + 8] += xv[rr].w * ev[kk].w;
                        }
                }
            }
        }
        if (kt == 0) {
            __syncthreads();   // a_lds complete before epilogue reads
#pragma unroll
            for (int rr = 0; rr < 8; ++rr) a_reg[rr] = a_lds[tr + rr * 16];
        }
        // epilogue: d = fl(fl(a + b_k) - 2*m), running first-min (k ascending per thread)
#pragma unroll
        for (int kk = 0; kk < 16; ++kk) {
            int kl = tk + kk * 16;
            float b = bk[k0 + kl];
#pragma unroll
            for (int rr = 0; rr < 8; ++rr) {
                float t = a_reg[rr] + b;
                float d = t - 2.0f * m[rr][kk];
                if (d < minv[rr]) { minv[rr] = d; mini[rr] = k0 + kl; }
            }
        }
    }

    // cross-thread (over tk) reduce with first-index tie-break, then global atomicMin
    __syncthreads();
    float (*pv)[16] = reinterpret_cast<float(*)[16]>(&x_lds[0][0]);
    int   (*pi)[16] = reinterpret_cast<int(*)[16]>(&e_lds[0][0]);
#pragma unroll
    for (int rr = 0; rr < 8; ++rr) {
        pv[tr + rr * 16][tk] = minv[rr];
        pi[tr + rr * 16][tk] = mini[rr];
    }
    __syncthreads();
    if (tid < 128) {
        float bv = pv[tid][0];
        int   bi = pi[tid][0];
#pragma unroll
        for (int j = 1; j < 16; ++j) {
            float v = pv[tid][j];
            int   i = pi[tid][j];
            if (v < bv || (v == bv && i < bi)) { bv = v; bi = i; }
        }
        // d > 0 always (squared L2 of ~unit-norm rows) -> fp32 bits order-preserving.
        // key = (d_bits << 32) | k : u64 min == (min d, then min k) == numpy argmin
        unsigned long long key = ((unsigned long long)__float_as_uint(bv) << 32)
                               | (unsigned long long)(unsigned)bi;
        atomicMin(&amin[row0 + tid], key);
    }
}

// ---------------- extract index, histogram, one-hot scatter ----------------
__global__ void vq_combine_kernel(const unsigned long long* __restrict__ amin,
                                  int* __restrict__ idx_ws,
                                  int* __restrict__ counts,
                                  float* __restrict__ enc) {
    int n = blockIdx.x * 256 + threadIdx.x;
    if (n >= N_ROWS) return;
    int bi = (int)(unsigned)(amin[n] & 0xFFFFFFFFull);
    idx_ws[n] = bi;
    atomicAdd(&counts[bi], 1);
    enc[(size_t)n * K_EMB + bi] = 1.0f;
}

// ---------------- quantized output + loss reduction ----------------
// block handles 64 consecutive n (one image), LDS-transposed emb gather
__global__ void vq_quant_loss_kernel(const float* __restrict__ xin,
                                     const float* __restrict__ emb,
                                     const int* __restrict__ idx_ws,
                                     float* __restrict__ out,
                                     double* __restrict__ acc) {
    __shared__ float q_lds[64][257];
    __shared__ int   k_lds[64];
    const int tid = threadIdx.x;
    const int n0  = blockIdx.x * 64;
    const int b_img = n0 >> 10;
    const int hw0   = n0 & 1023;

    if (tid < 64) k_lds[tid] = idx_ws[n0 + tid];
    __syncthreads();
    // gather 64 emb rows (coalesced float4 per row), scalar LDS writes
#pragma unroll
    for (int p = 0; p < 16; ++p) {
        int idx = tid + p * 256;      // 0..4095
        int row = idx >> 6;           // 0..63
        int c4  = idx & 63;
        float4 q = reinterpret_cast<const float4*>(emb)[(size_t)k_lds[row] * 64 + c4];
        q_lds[row][c4 * 4 + 0] = q.x;
        q_lds[row][c4 * 4 + 1] = q.y;
        q_lds[row][c4 * 4 + 2] = q.z;
        q_lds[row][c4 * 4 + 3] = q.w;
    }
    __syncthreads();

    double local = 0.0;
    const size_t base = (size_t)b_img * (C_DIM * 1024) + hw0;
    const int hw = tid & 63;
    const int cb = tid >> 6;          // 0..3
    for (int pass = 0; pass < 64; ++pass) {
        int c = pass * 4 + cb;
        size_t off = base + (size_t)c * 1024 + hw;
        float x = xin[off];
        float q = q_lds[hw][c];
        float dq = q - x;                    // fl(q - x)
        out[QUANT_OFF + off] = x + dq;       // straight-through: fl(x + fl(q-x))
        local += (double)dq * (double)dq;
    }
#pragma unroll
    for (int o = 32; o > 0; o >>= 1) local += __shfl_down(local, o, 64);
    __shared__ double wsum[4];
    if ((threadIdx.x & 63) == 0) wsum[threadIdx.x >> 6] = local;
    __syncthreads();
    if (threadIdx.x == 0) atomicAdd(acc, wsum[0] + wsum[1] + wsum[2] + wsum[3]);
}

// ---------------- perplexity + loss finalize ----------------
__global__ void vq_finalize_kernel(const int* __restrict__ counts,
                                   const double* __restrict__ acc,
                                   float* __restrict__ out) {
    double s = 0.0;
    for (int k = threadIdx.x; k < K_EMB; k += 256) {
        int c = counts[k];
        if (c > 0) {
            double p = (double)c * (1.0 / 16384.0);
            s += p * log(p + 1e-10);
        }
    }
#pragma unroll
    for (int o = 32; o > 0; o >>= 1) s += __shfl_down(s, o, 64);
    __shared__ double wsum[4];
    if ((threadIdx.x & 63) == 0) wsum[threadIdx.x >> 6] = s;
    __syncthreads();
    if (threadIdx.x == 0) {
        double tot = wsum[0] + wsum[1] + wsum[2] + wsum[3];
        out[PERP_OFF] = (float)exp(-tot);
        float l = (float)(acc[0] * (1.0 / (double)QUANT_N));
        out[0] = l + 0.25f * l;   // q_latent + 0.25 * e_latent (numerically equal arrays)
    }
}

extern "C" void kernel_launch(void* const* d_in, const int* in_sizes, int n_in,
                              void* d_out, int out_size, void* d_ws, size_t ws_size,
                              hipStream_t stream) {
    const float* xin = (const float*)d_in[0];
    const float* emb = (const float*)d_in[1];
    float* out = (float*)d_out;
    float* ws  = (float*)d_ws;

    float*              bk     = ws + WS_BK;
    unsigned long long* amin   = (unsigned long long*)(ws + WS_AMIN);
    int*                idx_ws = (int*)(ws + WS_IDX);
    int*                counts = (int*)(ws + WS_CNT);
    double*             acc    = (double*)(ws + WS_ACC);

    // zero the one-hot region, histogram, loss accumulator; amin -> u64 max
    hipMemsetAsync(out + ENC_OFF, 0, (size_t)N_ROWS * K_EMB * sizeof(float), stream);
    hipMemsetAsync(counts, 0, K_EMB * sizeof(int), stream);
    hipMemsetAsync(acc, 0, 16, stream);
    hipMemsetAsync(amin, 0xFF, (size_t)N_ROWS * 8, stream);

    vq_bk_kernel<<<K_EMB / 4, 256, 0, stream>>>(emb, bk);
    vq_argmin_kernel<<<128 * NSPLIT, 256, 0, stream>>>(xin, emb, bk, amin);
    vq_combine_kernel<<<N_ROWS / 256, 256, 0, stream>>>(amin, idx_ws, counts, out + ENC_OFF);
    vq_quant_loss_kernel<<<N_ROWS / 64, 256, 0, stream>>>(xin, emb, idx_ws, out, acc);
    vq_finalize_kernel<<<1, 256, 0, stream>>>(counts, acc, out);
}

// Round 4
// 16104.922 us; speedup vs baseline: 1.7837x; 1.7837x over previous
//
#include <hip/hip_runtime.h>
#include <math.h>

#define N_ROWS   16384
#define K_EMB    8192
#define C_DIM    256
#define QUANT_N  4194304      // 16*256*32*32
#define QUANT_OFF 1
#define PERP_OFF  4194305
#define ENC_OFF   4194306

#define CAND_CAP 128

// ws layout in 4-byte units
#define WS_BK    0                          // 8192 f32
#define WS_AN    8192                       // 16384 f32
#define WS_AMIN  24576                      // 16384 u64
#define WS_CCNT  57344                      // 16384 u32
#define WS_CAND  73728                      // 16384*128 u64 = 4194304 slots
#define WS_IDX   4268032                    // 16384 i32
#define WS_CNT   4284416                    // 8192 i32
#define WS_ACC   4292608                    // 1 double (+pad)
#define WS_XH    4292616                    // 16384*256 bf16 = 2097152 slots
#define WS_EH    6389768                    // 8192*256 bf16 = 1048576 slots
// end: 7438344 f32 = 29.8 MB

typedef __attribute__((ext_vector_type(8))) short short8_t;
typedef __attribute__((ext_vector_type(4))) float f32x4;
typedef __attribute__((ext_vector_type(8))) unsigned short u16x8;

__device__ __forceinline__ unsigned short f2bf(float f) {
    unsigned int u = __float_as_uint(f);
    u += 0x7FFFu + ((u >> 16) & 1u);        // RNE (inputs are finite normals)
    return (unsigned short)(u >> 16);
}

// ---------------- b_k = sum(emb[k,:]^2) (unchanged: same bitwise b as rounds 1-3) ----------------
__global__ void vq_bk_kernel(const float* __restrict__ emb, float* __restrict__ bk) {
    int row  = blockIdx.x * 4 + (threadIdx.x >> 6);
    int lane = threadIdx.x & 63;
    float4 v = reinterpret_cast<const float4*>(emb)[(size_t)row * 64 + lane];
    float s = v.x * v.x + v.y * v.y + v.z * v.z + v.w * v.w;
#pragma unroll
    for (int o = 32; o > 0; o >>= 1) s += __shfl_down(s, o, 64);
    if (lane == 0) bk[row] = s;
}

// ---------------- a_n = sum(x_n^2), strict ascending-c fmaf chain (bitwise == rounds 1-3) ----------------
__global__ void vq_an_kernel(const float* __restrict__ xin, float* __restrict__ an) {
    int n = blockIdx.x * 256 + threadIdx.x;
    int b = n >> 10, hw = n & 1023;
    const float* xr = xin + (size_t)b * (C_DIM * 1024) + hw;
    float s = 0.f;
    for (int c = 0; c < C_DIM; ++c) { float v = xr[(size_t)c * 1024]; s = fmaf(v, v, s); }
    an[n] = s;
}

// ---------------- pack x -> bf16 [n][c] row-major (transpose via LDS) ----------------
__global__ void vq_packx_kernel(const float* __restrict__ xin, unsigned short* __restrict__ xh) {
    __shared__ float tile[64][65];
    const int t = threadIdx.x;
    const int nb = blockIdx.x >> 2;
    const int cb = blockIdx.x & 3;
    const int n0 = nb * 64;
    const int b  = n0 >> 10, hw0 = n0 & 1023;
    {
        int cl = t >> 6, nl = t & 63;
#pragma unroll
        for (int i = 0; i < 16; ++i) {
            int c = cb * 64 + cl * 16 + i;
            tile[cl * 16 + i][nl] = xin[(size_t)b * (C_DIM * 1024) + (size_t)c * 1024 + hw0 + nl];
        }
    }
    __syncthreads();
    {
        int nl = t >> 2, cq = t & 3;
#pragma unroll
        for (int j = 0; j < 2; ++j) {
            u16x8 v;
#pragma unroll
            for (int jj = 0; jj < 8; ++jj) v[jj] = f2bf(tile[cq * 16 + j * 8 + jj][nl]);
            *reinterpret_cast<u16x8*>(&xh[(size_t)(n0 + nl) * 256 + cb * 64 + cq * 16 + j * 8]) = v;
        }
    }
}

// ---------------- pack emb -> bf16 [k][c] ----------------
__global__ void vq_packe_kernel(const float* __restrict__ emb, unsigned short* __restrict__ eh) {
    int flat = blockIdx.x * 256 + threadIdx.x;   // 0..131071
    int k = flat >> 4, c16 = flat & 15;
    const float4* src = reinterpret_cast<const float4*>(emb) + (size_t)k * 64 + c16 * 4;
#pragma unroll
    for (int j = 0; j < 2; ++j) {
        float4 v0 = src[j * 2], v1 = src[j * 2 + 1];
        u16x8 v;
        v[0]=f2bf(v0.x); v[1]=f2bf(v0.y); v[2]=f2bf(v0.z); v[3]=f2bf(v0.w);
        v[4]=f2bf(v1.x); v[5]=f2bf(v1.y); v[6]=f2bf(v1.z); v[7]=f2bf(v1.w);
        *reinterpret_cast<u16x8*>(&eh[(size_t)k * 256 + c16 * 16 + j * 8]) = v;
    }
}

// ---------------- MFMA distance + approx-argmin + candidate collection ----------------
// grid 4096: rb = bid>>5 (128 x-rows), kb = bid&31 (256 emb-ks). 256 threads, 4 waves.
// D[k][xrow] = mfma(A=emb_frag, B=x_frag): lane holds xrow = rt*16+(l&15), k = kt*16+(l>>4)*4+reg
__launch_bounds__(256, 2)
__global__ void vq_mfma_kernel(const unsigned short* __restrict__ xh,
                               const unsigned short* __restrict__ eh,
                               const float* __restrict__ an,
                               const float* __restrict__ bk,
                               unsigned long long* __restrict__ amin,
                               unsigned int* __restrict__ ccnt,
                               unsigned long long* __restrict__ cand) {
    __shared__ unsigned short e_lds[256][72];
    __shared__ unsigned short x_lds[128][72];
    const int t  = threadIdx.x;
    const int rb = blockIdx.x >> 5;
    const int kb = blockIdx.x & 31;
    const int w  = t >> 6;
    const int l  = t & 63;
    const int lr = l & 15;
    const int lg = l >> 4;

    f32x4 acc[4][8];
#pragma unroll
    for (int kt = 0; kt < 4; ++kt)
#pragma unroll
        for (int rt = 0; rt < 8; ++rt) acc[kt][rt] = (f32x4){0.f, 0.f, 0.f, 0.f};

    const unsigned short* xbase = xh + (size_t)(rb * 128) * 256;
    const unsigned short* ebase = eh + (size_t)(kb * 256) * 256;

    for (int cc = 0; cc < 4; ++cc) {
        __syncthreads();
        // stage e: 256 k x 64 c
#pragma unroll
        for (int i = 0; i < 8; ++i) {
            int flat = t + 256 * i;
            int kr = flat >> 3, u8 = flat & 7;
            *reinterpret_cast<u16x8*>(&e_lds[kr][u8 * 8]) =
                *reinterpret_cast<const u16x8*>(&ebase[(size_t)kr * 256 + cc * 64 + u8 * 8]);
        }
        // stage x: 128 rows x 64 c
#pragma unroll
        for (int i = 0; i < 4; ++i) {
            int flat = t + 256 * i;
            int xr = flat >> 3, u8 = flat & 7;
            *reinterpret_cast<u16x8*>(&x_lds[xr][u8 * 8]) =
                *reinterpret_cast<const u16x8*>(&xbase[(size_t)xr * 256 + cc * 64 + u8 * 8]);
        }
        __syncthreads();
#pragma unroll
        for (int step = 0; step < 2; ++step) {
            const int cl = step * 32 + lg * 8;
            short8_t af[4], bf[8];
#pragma unroll
            for (int kt = 0; kt < 4; ++kt)
                af[kt] = *reinterpret_cast<const short8_t*>(&e_lds[w * 64 + kt * 16 + lr][cl]);
#pragma unroll
            for (int rt = 0; rt < 8; ++rt)
                bf[rt] = *reinterpret_cast<const short8_t*>(&x_lds[rt * 16 + lr][cl]);
#pragma unroll
            for (int kt = 0; kt < 4; ++kt)
#pragma unroll
                for (int rt = 0; rt < 8; ++rt)
                    acc[kt][rt] = __builtin_amdgcn_mfma_f32_16x16x32_bf16(af[kt], bf[rt], acc[kt][rt], 0, 0, 0);
        }
    }

    // epilogue
    float bvals[16];
#pragma unroll
    for (int kt = 0; kt < 4; ++kt)
#pragma unroll
        for (int reg = 0; reg < 4; ++reg)
            bvals[kt * 4 + reg] = bk[kb * 256 + w * 64 + kt * 16 + lg * 4 + reg];

#pragma unroll
    for (int rt = 0; rt < 8; ++rt) {
        const int row = rb * 128 + rt * 16 + lr;
        const float a_r = an[row];
        float dv[16];
        float mn = 3.402823466e38f; int mk = 0;
#pragma unroll
        for (int kt = 0; kt < 4; ++kt)
#pragma unroll
            for (int reg = 0; reg < 4; ++reg) {
                float m = acc[kt][rt][reg];
                float tt = a_r + bvals[kt * 4 + reg];
                float d = fmaf(-2.f, m, tt);
                dv[kt * 4 + reg] = d;
                int k = kb * 256 + w * 64 + kt * 16 + lg * 4 + reg;
                if (d < mn) { mn = d; mk = k; }
            }
        unsigned long long key = ((unsigned long long)__float_as_uint(mn) << 32) | (unsigned)mk;
        unsigned long long o1 = __shfl_xor(key, 16, 64); key = o1 < key ? o1 : key;
        unsigned long long o2 = __shfl_xor(key, 32, 64); key = o2 < key ? o2 : key;
        if (lg == 0) atomicMin(&amin[row], key);
        // racy read of running min: only ever >= final -> superset-safe candidate filter
        unsigned long long obs = amin[row];
        if (key < obs) obs = key;
        float obs_d = __uint_as_float((unsigned)(obs >> 32));
        float thr = obs_d + fmaf(8.75e-5f, sqrtf(a_r), 1.25e-4f);
#pragma unroll
        for (int i = 0; i < 16; ++i) {
            if (dv[i] <= thr) {
                int k = kb * 256 + w * 64 + (i >> 2) * 16 + lg * 4 + (i & 3);
                unsigned pos = atomicAdd(&ccnt[row], 1u);
                if (pos < CAND_CAP)
                    cand[(size_t)row * CAND_CAP + pos] =
                        ((unsigned long long)__float_as_uint(dv[i]) << 32) | (unsigned)k;
            }
        }
    }
}

// ---------------- exact re-check of candidates, histogram, one-hot ----------------
__global__ void vq_select_kernel(const float* __restrict__ xin,
                                 const float* __restrict__ emb,
                                 const float* __restrict__ an,
                                 const float* __restrict__ bk,
                                 const unsigned long long* __restrict__ amin,
                                 const unsigned int* __restrict__ ccnt,
                                 const unsigned long long* __restrict__ cand,
                                 int* __restrict__ idx_ws,
                                 int* __restrict__ counts,
                                 float* __restrict__ enc) {
    int r = blockIdx.x * 256 + threadIdx.x;
    const float a_r = an[r];
    const unsigned cnt = ccnt[r];
    const int b = r >> 10, hw = r & 1023;
    const float* xr = xin + (size_t)b * (C_DIM * 1024) + hw;

    float best_d = 3.402823466e38f; int best_k = 0x7FFFFFFF;
    if (cnt > CAND_CAP) {
        // deterministic fallback: full exact scan (never expected)
        for (int k = 0; k < K_EMB; ++k) {
            const float* e = emb + (size_t)k * C_DIM;
            float m = 0.f;
            for (int c = 0; c < C_DIM; ++c) m = fmaf(xr[(size_t)c * 1024], e[c], m);
            float d = fmaf(-2.f, m, a_r + bk[k]);
            if (d < best_d || (d == best_d && k < best_k)) { best_d = d; best_k = k; }
        }
    } else {
        float glob = __uint_as_float((unsigned)(amin[r] >> 32));
        float thr = glob + fmaf(7.0e-5f, sqrtf(a_r), 1.0e-4f);
        for (unsigned i = 0; i < cnt; ++i) {
            unsigned long long e64 = cand[(size_t)r * CAND_CAP + i];
            float dt = __uint_as_float((unsigned)(e64 >> 32));
            if (dt <= thr) {
                int k = (int)(unsigned)(e64 & 0xFFFFFFFFull);
                const float* e = emb + (size_t)k * C_DIM;
                float m = 0.f;
                for (int c = 0; c < C_DIM; ++c) m = fmaf(xr[(size_t)c * 1024], e[c], m);
                float d = fmaf(-2.f, m, a_r + bk[k]);   // fl(fl(a+b) - 2m), bitwise == rounds 1-3
                if (d < best_d || (d == best_d && k < best_k)) { best_d = d; best_k = k; }
            }
        }
    }
    idx_ws[r] = best_k;
    atomicAdd(&counts[best_k], 1);
    enc[(size_t)r * K_EMB + best_k] = 1.0f;
}

// ---------------- quantized output + loss reduction ----------------
__global__ void vq_quant_loss_kernel(const float* __restrict__ xin,
                                     const float* __restrict__ emb,
                                     const int* __restrict__ idx_ws,
                                     float* __restrict__ out,
                                     double* __restrict__ acc) {
    __shared__ float q_lds[64][257];
    __shared__ int   k_lds[64];
    const int tid = threadIdx.x;
    const int n0  = blockIdx.x * 64;
    const int b_img = n0 >> 10;
    const int hw0   = n0 & 1023;

    if (tid < 64) k_lds[tid] = idx_ws[n0 + tid];
    __syncthreads();
#pragma unroll
    for (int p = 0; p < 16; ++p) {
        int idx = tid + p * 256;
        int row = idx >> 6;
        int c4  = idx & 63;
        float4 q = reinterpret_cast<const float4*>(emb)[(size_t)k_lds[row] * 64 + c4];
        q_lds[row][c4 * 4 + 0] = q.x;
        q_lds[row][c4 * 4 + 1] = q.y;
        q_lds[row][c4 * 4 + 2] = q.z;
        q_lds[row][c4 * 4 + 3] = q.w;
    }
    __syncthreads();

    double local = 0.0;
    const size_t base = (size_t)b_img * (C_DIM * 1024) + hw0;
    const int hw = tid & 63;
    const int cb = tid >> 6;
    for (int pass = 0; pass < 64; ++pass) {
        int c = pass * 4 + cb;
        size_t off = base + (size_t)c * 1024 + hw;
        float x = xin[off];
        float q = q_lds[hw][c];
        float dq = q - x;
        out[QUANT_OFF + off] = x + dq;
        local += (double)dq * (double)dq;
    }
#pragma unroll
    for (int o = 32; o > 0; o >>= 1) local += __shfl_down(local, o, 64);
    __shared__ double wsum[4];
    if ((threadIdx.x & 63) == 0) wsum[threadIdx.x >> 6] = local;
    __syncthreads();
    if (threadIdx.x == 0) atomicAdd(acc, wsum[0] + wsum[1] + wsum[2] + wsum[3]);
}

// ---------------- perplexity + loss finalize ----------------
__global__ void vq_finalize_kernel(const int* __restrict__ counts,
                                   const double* __restrict__ acc,
                                   float* __restrict__ out) {
    double s = 0.0;
    for (int k = threadIdx.x; k < K_EMB; k += 256) {
        int c = counts[k];
        if (c > 0) {
            double p = (double)c * (1.0 / 16384.0);
            s += p * log(p + 1e-10);
        }
    }
#pragma unroll
    for (int o = 32; o > 0; o >>= 1) s += __shfl_down(s, o, 64);
    __shared__ double wsum[4];
    if ((threadIdx.x & 63) == 0) wsum[threadIdx.x >> 6] = s;
    __syncthreads();
    if (threadIdx.x == 0) {
        double tot = wsum[0] + wsum[1] + wsum[2] + wsum[3];
        out[PERP_OFF] = (float)exp(-tot);
        float l = (float)(acc[0] * (1.0 / (double)QUANT_N));
        out[0] = l + 0.25f * l;
    }
}

extern "C" void kernel_launch(void* const* d_in, const int* in_sizes, int n_in,
                              void* d_out, int out_size, void* d_ws, size_t ws_size,
                              hipStream_t stream) {
    const float* xin = (const float*)d_in[0];
    const float* emb = (const float*)d_in[1];
    float* out = (float*)d_out;
    float* ws  = (float*)d_ws;

    float*              bk     = ws + WS_BK;
    float*              an     = ws + WS_AN;
    unsigned long long* amin   = (unsigned long long*)(ws + WS_AMIN);
    unsigned int*       ccnt   = (unsigned int*)(ws + WS_CCNT);
    unsigned long long* cand   = (unsigned long long*)(ws + WS_CAND);
    int*                idx_ws = (int*)(ws + WS_IDX);
    int*                counts = (int*)(ws + WS_CNT);
    double*             acc    = (double*)(ws + WS_ACC);
    unsigned short*     xh     = (unsigned short*)(ws + WS_XH);
    unsigned short*     eh     = (unsigned short*)(ws + WS_EH);

    hipMemsetAsync(out + ENC_OFF, 0, (size_t)N_ROWS * K_EMB * sizeof(float), stream);
    hipMemsetAsync(counts, 0, K_EMB * sizeof(int), stream);
    hipMemsetAsync(acc, 0, 16, stream);
    hipMemsetAsync(ccnt, 0, N_ROWS * sizeof(unsigned int), stream);
    hipMemsetAsync(amin, 0xFF, (size_t)N_ROWS * 8, stream);

    vq_bk_kernel<<<K_EMB / 4, 256, 0, stream>>>(emb, bk);
    vq_an_kernel<<<N_ROWS / 256, 256, 0, stream>>>(xin, an);
    vq_packx_kernel<<<(N_ROWS / 64) * 4, 256, 0, stream>>>(xin, xh);
    vq_packe_kernel<<<(K_EMB * 16) / 256, 256, 0, stream>>>(emb, eh);
    vq_mfma_kernel<<<128 * 32, 256, 0, stream>>>(xh, eh, an, bk, amin, ccnt, cand);
    vq_select_kernel<<<N_ROWS / 256, 256, 0, stream>>>(xin, emb, an, bk, amin, ccnt, cand,
                                                       idx_ws, counts, out + ENC_OFF);
    vq_quant_loss_kernel<<<N_ROWS / 64, 256, 0, stream>>>(xin, emb, idx_ws, out, acc);
    vq_finalize_kernel<<<1, 256, 0, stream>>>(counts, acc, out);
}

// Round 5
// 886.947 us; speedup vs baseline: 32.3883x; 18.1577x over previous
//
#include <hip/hip_runtime.h>
#include <math.h>

#define N_ROWS   16384
#define K_EMB    8192
#define C_DIM    256
#define QUANT_N  4194304      // 16*256*32*32
#define QUANT_OFF 1
#define PERP_OFF  4194305
#define ENC_OFF   4194306

#define CAND_CAP 128

// ws layout in 4-byte units (identical footprint to round 4, which fit)
#define WS_BK    0                          // 8192 f32
#define WS_AN    8192                       // 16384 f32
#define WS_AMIN  24576                      // 16384 u64
#define WS_CCNT  57344                      // 16384 u32
#define WS_CAND  73728                      // 16384*128 u64
#define WS_IDX   4268032                    // 16384 i32
#define WS_CNT   4284416                    // 8192 i32
#define WS_ACC   4292608                    // 1 double (+pad)
#define WS_XH    4292616                    // 16384*256 bf16
#define WS_EH    6389768                    // 8192*256 bf16

typedef __attribute__((ext_vector_type(8))) short short8_t;
typedef __attribute__((ext_vector_type(4))) float f32x4;
typedef __attribute__((ext_vector_type(8))) unsigned short u16x8;
typedef unsigned long long ull;

__device__ __forceinline__ unsigned short f2bf(float f) {
    unsigned int u = __float_as_uint(f);
    u += 0x7FFFu + ((u >> 16) & 1u);        // RNE (inputs are finite normals)
    return (unsigned short)(u >> 16);
}

// ---------------- b_k = sum(emb[k,:]^2) ----------------
__global__ void vq_bk_kernel(const float* __restrict__ emb, float* __restrict__ bk) {
    int row  = blockIdx.x * 4 + (threadIdx.x >> 6);
    int lane = threadIdx.x & 63;
    float4 v = reinterpret_cast<const float4*>(emb)[(size_t)row * 64 + lane];
    float s = v.x * v.x + v.y * v.y + v.z * v.z + v.w * v.w;
#pragma unroll
    for (int o = 32; o > 0; o >>= 1) s += __shfl_down(s, o, 64);
    if (lane == 0) bk[row] = s;
}

// ---------------- a_n = sum(x_n^2), sequential ascending-c fmaf (== round 4) ----------------
__global__ void vq_an_kernel(const float* __restrict__ xin, float* __restrict__ an) {
    int n = blockIdx.x * 256 + threadIdx.x;
    int b = n >> 10, hw = n & 1023;
    const float* xr = xin + (size_t)b * (C_DIM * 1024) + hw;
    float s = 0.f;
    for (int c = 0; c < C_DIM; ++c) { float v = xr[(size_t)c * 1024]; s = fmaf(v, v, s); }
    an[n] = s;
}

// ---------------- pack x -> bf16 [n][c] row-major (transpose via LDS) ----------------
__global__ void vq_packx_kernel(const float* __restrict__ xin, unsigned short* __restrict__ xh) {
    __shared__ float tile[64][65];
    const int t = threadIdx.x;
    const int nb = blockIdx.x >> 2;
    const int cb = blockIdx.x & 3;
    const int n0 = nb * 64;
    const int b  = n0 >> 10, hw0 = n0 & 1023;
    {
        int cl = t >> 6, nl = t & 63;
#pragma unroll
        for (int i = 0; i < 16; ++i) {
            int c = cb * 64 + cl * 16 + i;
            tile[cl * 16 + i][nl] = xin[(size_t)b * (C_DIM * 1024) + (size_t)c * 1024 + hw0 + nl];
        }
    }
    __syncthreads();
    {
        int nl = t >> 2, cq = t & 3;
#pragma unroll
        for (int j = 0; j < 2; ++j) {
            u16x8 v;
#pragma unroll
            for (int jj = 0; jj < 8; ++jj) v[jj] = f2bf(tile[cq * 16 + j * 8 + jj][nl]);
            *reinterpret_cast<u16x8*>(&xh[(size_t)(n0 + nl) * 256 + cb * 64 + cq * 16 + j * 8]) = v;
        }
    }
}

// ---------------- pack emb -> bf16 [k][c] ----------------
__global__ void vq_packe_kernel(const float* __restrict__ emb, unsigned short* __restrict__ eh) {
    int flat = blockIdx.x * 256 + threadIdx.x;
    int k = flat >> 4, c16 = flat & 15;
    const float4* src = reinterpret_cast<const float4*>(emb) + (size_t)k * 64 + c16 * 4;
#pragma unroll
    for (int j = 0; j < 2; ++j) {
        float4 v0 = src[j * 2], v1 = src[j * 2 + 1];
        u16x8 v;
        v[0]=f2bf(v0.x); v[1]=f2bf(v0.y); v[2]=f2bf(v0.z); v[3]=f2bf(v0.w);
        v[4]=f2bf(v1.x); v[5]=f2bf(v1.y); v[6]=f2bf(v1.z); v[7]=f2bf(v1.w);
        *reinterpret_cast<u16x8*>(&eh[(size_t)k * 256 + c16 * 16 + j * 8]) = v;
    }
}

// ---------------- MFMA distance + approx-argmin + tight candidate collection ----------------
__launch_bounds__(256, 2)
__global__ void vq_mfma_kernel(const unsigned short* __restrict__ xh,
                               const unsigned short* __restrict__ eh,
                               const float* __restrict__ an,
                               const float* __restrict__ bk,
                               ull* __restrict__ amin,
                               unsigned int* __restrict__ ccnt,
                               ull* __restrict__ cand) {
    __shared__ unsigned short e_lds[256][72];
    __shared__ unsigned short x_lds[128][72];
    __shared__ ull key_lds[128][4];
    const int t  = threadIdx.x;
    const int rb = blockIdx.x >> 5;
    const int kb = blockIdx.x & 31;
    const int w  = t >> 6;
    const int l  = t & 63;
    const int lr = l & 15;
    const int lg = l >> 4;

    f32x4 acc[4][8];
#pragma unroll
    for (int kt = 0; kt < 4; ++kt)
#pragma unroll
        for (int rt = 0; rt < 8; ++rt) acc[kt][rt] = (f32x4){0.f, 0.f, 0.f, 0.f};

    const unsigned short* xbase = xh + (size_t)(rb * 128) * 256;
    const unsigned short* ebase = eh + (size_t)(kb * 256) * 256;

    for (int cc = 0; cc < 4; ++cc) {
        __syncthreads();
#pragma unroll
        for (int i = 0; i < 8; ++i) {
            int flat = t + 256 * i;
            int kr = flat >> 3, u8 = flat & 7;
            *reinterpret_cast<u16x8*>(&e_lds[kr][u8 * 8]) =
                *reinterpret_cast<const u16x8*>(&ebase[(size_t)kr * 256 + cc * 64 + u8 * 8]);
        }
#pragma unroll
        for (int i = 0; i < 4; ++i) {
            int flat = t + 256 * i;
            int xr = flat >> 3, u8 = flat & 7;
            *reinterpret_cast<u16x8*>(&x_lds[xr][u8 * 8]) =
                *reinterpret_cast<const u16x8*>(&xbase[(size_t)xr * 256 + cc * 64 + u8 * 8]);
        }
        __syncthreads();
#pragma unroll
        for (int step = 0; step < 2; ++step) {
            const int cl = step * 32 + lg * 8;
            short8_t af[4], bf[8];
#pragma unroll
            for (int kt = 0; kt < 4; ++kt)
                af[kt] = *reinterpret_cast<const short8_t*>(&e_lds[w * 64 + kt * 16 + lr][cl]);
#pragma unroll
            for (int rt = 0; rt < 8; ++rt)
                bf[rt] = *reinterpret_cast<const short8_t*>(&x_lds[rt * 16 + lr][cl]);
#pragma unroll
            for (int kt = 0; kt < 4; ++kt)
#pragma unroll
                for (int rt = 0; rt < 8; ++rt)
                    acc[kt][rt] = __builtin_amdgcn_mfma_f32_16x16x32_bf16(af[kt], bf[rt], acc[kt][rt], 0, 0, 0);
        }
    }

    float bvals[16];
#pragma unroll
    for (int kt = 0; kt < 4; ++kt)
#pragma unroll
        for (int reg = 0; reg < 4; ++reg)
            bvals[kt * 4 + reg] = bk[kb * 256 + w * 64 + kt * 16 + lg * 4 + reg];

    // pass 1: d into acc (in place), per-wave per-row min -> atomicMin + LDS
    float ar8[8];
#pragma unroll
    for (int rt = 0; rt < 8; ++rt) {
        const int row = rb * 128 + rt * 16 + lr;
        const float a_r = an[row];
        ar8[rt] = a_r;
        float mn = 3.402823466e38f; int mk = 0;
#pragma unroll
        for (int kt = 0; kt < 4; ++kt)
#pragma unroll
            for (int reg = 0; reg < 4; ++reg) {
                float d = fmaf(-2.f, acc[kt][rt][reg], a_r + bvals[kt * 4 + reg]);
                acc[kt][rt][reg] = d;
                int k = kb * 256 + w * 64 + kt * 16 + lg * 4 + reg;
                if (d < mn) { mn = d; mk = k; }
            }
        ull key = ((ull)__float_as_uint(mn) << 32) | (unsigned)mk;
        ull o1 = __shfl_xor(key, 16, 64); if (o1 < key) key = o1;
        ull o2 = __shfl_xor(key, 32, 64); if (o2 < key) key = o2;
        if (lg == 0) {
            atomicMin(&amin[row], key);
            key_lds[rt * 16 + lr][w] = key;
        }
    }
    __syncthreads();
    // pass 2: candidates vs (block-row min, racy global min) + tight margin
#pragma unroll
    for (int rt = 0; rt < 8; ++rt) {
        const int row = rb * 128 + rt * 16 + lr;
        ull bmin = key_lds[rt * 16 + lr][0];
#pragma unroll
        for (int j = 1; j < 4; ++j) { ull v = key_lds[rt * 16 + lr][j]; if (v < bmin) bmin = v; }
        ull obs = amin[row];              // racy: only ever >= final -> superset-safe
        if (obs < bmin) bmin = obs;
        float md  = __uint_as_float((unsigned)(bmin >> 32));
        float thr = md + fmaf(4.0e-5f, sqrtf(ar8[rt]), 1.6e-4f);   // 2*eps, 1.3x headroom
#pragma unroll
        for (int kt = 0; kt < 4; ++kt)
#pragma unroll
            for (int reg = 0; reg < 4; ++reg) {
                float d = acc[kt][rt][reg];
                if (d <= thr) {
                    int k = kb * 256 + w * 64 + kt * 16 + lg * 4 + reg;
                    unsigned pos = atomicAdd(&ccnt[row], 1u);
                    if (pos < CAND_CAP)
                        cand[(size_t)row * CAND_CAP + pos] =
                            ((ull)__float_as_uint(d) << 32) | (unsigned)k;
                }
            }
    }
}

// ---------------- exact re-check: one wave per row ----------------
__global__ void vq_select_kernel(const float* __restrict__ xin,
                                 const float* __restrict__ emb,
                                 const float* __restrict__ an,
                                 const float* __restrict__ bk,
                                 const ull* __restrict__ amin,
                                 const unsigned int* __restrict__ ccnt,
                                 const ull* __restrict__ cand,
                                 int* __restrict__ idx_ws,
                                 int* __restrict__ counts,
                                 float* __restrict__ enc) {
    __shared__ float xrow[4][260];
    const int w = threadIdx.x >> 6, l = threadIdx.x & 63;
    const int r = blockIdx.x * 4 + w;
    const int b = r >> 10, hw = r & 1023;
    const float* xr = xin + (size_t)b * (C_DIM * 1024) + hw;
#pragma unroll
    for (int i = 0; i < 4; ++i) xrow[w][l + 64 * i] = xr[(size_t)(l + 64 * i) * 1024];
    // same-wave LDS producer/consumer: compiler inserts lgkmcnt waits

    const unsigned cnt = ccnt[r];
    const float a_r = an[r];
    const float glob = __uint_as_float((unsigned)(amin[r] >> 32));
    const float thr  = glob + fmaf(4.0e-5f, sqrtf(a_r), 1.6e-4f);

    ull mykey = 0xFFFFFFFFFFFFFFFFull;
    if (cnt <= CAND_CAP) {
        for (unsigned i = l; i < cnt; i += 64) {
            ull e64 = cand[(size_t)r * CAND_CAP + i];
            float dt = __uint_as_float((unsigned)(e64 >> 32));
            if (dt <= thr) {
                int k = (int)(unsigned)(e64 & 0xFFFFFFFFull);
                const float* e = emb + (size_t)k * C_DIM;
                float m = 0.f;
                for (int c = 0; c < C_DIM; ++c) m = fmaf(xrow[w][c], e[c], m);
                float d = fmaf(-2.f, m, a_r + bk[k]);   // chain bitwise == round 4
                ull key = ((ull)__float_as_uint(d) << 32) | (unsigned)k;
                if (key < mykey) mykey = key;
            }
        }
    } else {
        // overflow fallback: wave-parallel exact full scan (rare, correct)
        for (int k = l; k < K_EMB; k += 64) {
            const float* e = emb + (size_t)k * C_DIM;
            float m = 0.f;
            for (int c = 0; c < C_DIM; ++c) m = fmaf(xrow[w][c], e[c], m);
            float d = fmaf(-2.f, m, a_r + bk[k]);
            ull key = ((ull)__float_as_uint(d) << 32) | (unsigned)k;
            if (key < mykey) mykey = key;
        }
    }
#pragma unroll
    for (int o = 32; o > 0; o >>= 1) {
        ull ok = __shfl_xor(mykey, o, 64);
        if (ok < mykey) mykey = ok;
    }
    if (l == 0) {
        int bi = (int)(unsigned)(mykey & 0xFFFFFFFFull);
        idx_ws[r] = bi;
        atomicAdd(&counts[bi], 1);
        enc[(size_t)r * K_EMB + bi] = 1.0f;
    }
}

// ---------------- quantized output + loss reduction ----------------
__global__ void vq_quant_loss_kernel(const float* __restrict__ xin,
                                     const float* __restrict__ emb,
                                     const int* __restrict__ idx_ws,
                                     float* __restrict__ out,
                                     double* __restrict__ acc) {
    __shared__ float q_lds[64][257];
    __shared__ int   k_lds[64];
    const int tid = threadIdx.x;
    const int n0  = blockIdx.x * 64;
    const int b_img = n0 >> 10;
    const int hw0   = n0 & 1023;

    if (tid < 64) k_lds[tid] = idx_ws[n0 + tid];
    __syncthreads();
#pragma unroll
    for (int p = 0; p < 16; ++p) {
        int idx = tid + p * 256;
        int row = idx >> 6;
        int c4  = idx & 63;
        float4 q = reinterpret_cast<const float4*>(emb)[(size_t)k_lds[row] * 64 + c4];
        q_lds[row][c4 * 4 + 0] = q.x;
        q_lds[row][c4 * 4 + 1] = q.y;
        q_lds[row][c4 * 4 + 2] = q.z;
        q_lds[row][c4 * 4 + 3] = q.w;
    }
    __syncthreads();

    double local = 0.0;
    const size_t base = (size_t)b_img * (C_DIM * 1024) + hw0;
    const int hw = tid & 63;
    const int cb = tid >> 6;
    for (int pass = 0; pass < 64; ++pass) {
        int c = pass * 4 + cb;
        size_t off = base + (size_t)c * 1024 + hw;
        float x = xin[off];
        float q = q_lds[hw][c];
        float dq = q - x;
        out[QUANT_OFF + off] = x + dq;
        local += (double)dq * (double)dq;
    }
#pragma unroll
    for (int o = 32; o > 0; o >>= 1) local += __shfl_down(local, o, 64);
    __shared__ double wsum[4];
    if ((threadIdx.x & 63) == 0) wsum[threadIdx.x >> 6] = local;
    __syncthreads();
    if (threadIdx.x == 0) atomicAdd(acc, wsum[0] + wsum[1] + wsum[2] + wsum[3]);
}

// ---------------- perplexity + loss finalize ----------------
__global__ void vq_finalize_kernel(const int* __restrict__ counts,
                                   const double* __restrict__ acc,
                                   float* __restrict__ out) {
    double s = 0.0;
    for (int k = threadIdx.x; k < K_EMB; k += 256) {
        int c = counts[k];
        if (c > 0) {
            double p = (double)c * (1.0 / 16384.0);
            s += p * log(p + 1e-10);
        }
    }
#pragma unroll
    for (int o = 32; o > 0; o >>= 1) s += __shfl_down(s, o, 64);
    __shared__ double wsum[4];
    if ((threadIdx.x & 63) == 0) wsum[threadIdx.x >> 6] = s;
    __syncthreads();
    if (threadIdx.x == 0) {
        double tot = wsum[0] + wsum[1] + wsum[2] + wsum[3];
        out[PERP_OFF] = (float)exp(-tot);
        float l = (float)(acc[0] * (1.0 / (double)QUANT_N));
        out[0] = l + 0.25f * l;
    }
}

extern "C" void kernel_launch(void* const* d_in, const int* in_sizes, int n_in,
                              void* d_out, int out_size, void* d_ws, size_t ws_size,
                              hipStream_t stream) {
    const float* xin = (const float*)d_in[0];
    const float* emb = (const float*)d_in[1];
    float* out = (float*)d_out;
    float* ws  = (float*)d_ws;

    float*          bk     = ws + WS_BK;
    float*          an     = ws + WS_AN;
    ull*            amin   = (ull*)(ws + WS_AMIN);
    unsigned int*   ccnt   = (unsigned int*)(ws + WS_CCNT);
    ull*            cand   = (ull*)(ws + WS_CAND);
    int*            idx_ws = (int*)(ws + WS_IDX);
    int*            counts = (int*)(ws + WS_CNT);
    double*         acc    = (double*)(ws + WS_ACC);
    unsigned short* xh     = (unsigned short*)(ws + WS_XH);
    unsigned short* eh     = (unsigned short*)(ws + WS_EH);

    hipMemsetAsync(out + ENC_OFF, 0, (size_t)N_ROWS * K_EMB * sizeof(float), stream);
    hipMemsetAsync(counts, 0, K_EMB * sizeof(int), stream);
    hipMemsetAsync(acc, 0, 16, stream);
    hipMemsetAsync(ccnt, 0, N_ROWS * sizeof(unsigned int), stream);
    hipMemsetAsync(amin, 0xFF, (size_t)N_ROWS * 8, stream);

    vq_bk_kernel<<<K_EMB / 4, 256, 0, stream>>>(emb, bk);
    vq_an_kernel<<<N_ROWS / 256, 256, 0, stream>>>(xin, an);
    vq_packx_kernel<<<(N_ROWS / 64) * 4, 256, 0, stream>>>(xin, xh);
    vq_packe_kernel<<<(K_EMB * 16) / 256, 256, 0, stream>>>(emb, eh);
    vq_mfma_kernel<<<128 * 32, 256, 0, stream>>>(xh, eh, an, bk, amin, ccnt, cand);
    vq_select_kernel<<<N_ROWS / 4, 256, 0, stream>>>(xin, emb, an, bk, amin, ccnt, cand,
                                                     idx_ws, counts, out + ENC_OFF);
    vq_quant_loss_kernel<<<N_ROWS / 64, 256, 0, stream>>>(xin, emb, idx_ws, out, acc);
    vq_finalize_kernel<<<1, 256, 0, stream>>>(counts, acc, out);
}